// Round 5
// baseline (67980.164 us; speedup 1.0000x reference)
//
#include <hip/hip_runtime.h>
#include <math.h>

// KalmanNet forward, persistent cooperative kernel, T=2048 serial steps.
// Round 3 kernel (resubmit x2; rounds 3-4 benches timed out before running):
// fit GRU weight residency into the 128-VGPR budget instead of spilling.
// 250 blocks x 1024 threads (16 waves/CU, 4 waves/SIMD -> 128 VGPRs natural).
// TWO waves per hidden unit, each holding HALF the unit's Wih/Whh rows:
// wih[3][4]+whh[3][4] float4 = 96 weight VGPRs/lane. Halves combine via LDS
// within the block. W2/W1 streamed from L2. Delta atomics spread over 8
// cacheline-separated copies.

#define T_STEPS 2048
#define H1      1600
#define HID     2000
#define NBLK    250
#define NTHR    1024
#define RMAGIC  0x1357u

struct Params {
  const float *y, *f, *h, *m1x0, *hn0, *W1, *b1, *Wih, *Whh, *bih, *bhh, *W2, *b2, *W3, *b3;
  float* out;
  float* hn_g;    // [2*2000] double-buffered hidden state
  float* delta;   // [2][8][10*16] partial K@innov copies
  unsigned* bar;  // [0]=cnt, [32]=gen, [64]=ready
};

__device__ __forceinline__ float dot4(float4 w, float4 x, float acc) {
  acc = fmaf(w.x, x.x, acc); acc = fmaf(w.y, x.y, acc);
  acc = fmaf(w.z, x.z, acc); acc = fmaf(w.w, x.w, acc);
  return acc;
}

__device__ __forceinline__ float wave_reduce(float v) {
#pragma unroll
  for (int o = 32; o > 0; o >>= 1) v += __shfl_xor(v, o, 64);
  return v;
}

__device__ __forceinline__ float sigm(float x) { return 1.0f / (1.0f + expf(-x)); }

__device__ __forceinline__ void gbar(unsigned* cnt, unsigned* gen) {
  __syncthreads();
  if (threadIdx.x == 0) {
    __threadfence();
    unsigned g = __hip_atomic_load(gen, __ATOMIC_RELAXED, __HIP_MEMORY_SCOPE_AGENT);
    unsigned prev = __hip_atomic_fetch_add(cnt, 1u, __ATOMIC_RELAXED, __HIP_MEMORY_SCOPE_AGENT);
    if (prev == NBLK - 1) {
      __hip_atomic_store(cnt, 0u, __ATOMIC_RELAXED, __HIP_MEMORY_SCOPE_AGENT);
      __threadfence();
      __hip_atomic_store(gen, g + 1u, __ATOMIC_RELAXED, __HIP_MEMORY_SCOPE_AGENT);
    } else {
      while (__hip_atomic_load(gen, __ATOMIC_RELAXED, __HIP_MEMORY_SCOPE_AGENT) == g)
        __builtin_amdgcn_s_sleep(1);
    }
    __threadfence();
  }
  __syncthreads();
}

__global__ __launch_bounds__(NTHR, 4) void knet_kernel(Params p) {
  const int tid  = threadIdx.x;
  const int blk  = blockIdx.x;
  const int wv   = tid >> 6;      // 0..15
  const int lane = tid & 63;
  const int u    = blk * 8 + (wv >> 1);   // hidden unit, 0..1999 exact cover
  const int half = wv & 1;                // which half of the unit's rows

  __shared__ __align__(16) float a1_lds[1856];   // 1600 + zero pad to 464 f4
  __shared__ __align__(16) float hn_lds[2048];   // 2000 + zero pad to 512 f4
  __shared__ float f_lds[100], h_lds[100], b3_lds[100];
  __shared__ float w3t_lds[200];                 // this block's 2 W3^T rows
  __shared__ float xin_lds[20];
  __shared__ float post_lds[10], prpv_lds[10], prior_lds[10], innov_lds[10];
  __shared__ float gpart_lds[16][4];             // per-wave gate partials
  __shared__ float a2part_lds[16];
  __shared__ float a2_lds[2], b2_lds[2];
  __shared__ float bih_l[24], bhh_l[24];         // [gate][unit-in-block]

  // ---------------- setup ----------------
  if (tid < 100) { f_lds[tid] = p.f[tid]; h_lds[tid] = p.h[tid]; b3_lds[tid] = p.b3[tid]; }
  if (tid < 10)  { post_lds[tid] = p.m1x0[tid]; prpv_lds[tid] = p.m1x0[tid]; }
  if (tid < 500) ((float4*)hn_lds)[tid] = ((const float4*)p.hn0)[tid];
  if (tid < 48)  hn_lds[2000 + tid] = 0.f;
  if (tid < 256) a1_lds[1600 + tid] = 0.f;
  if (tid < 24) {
    bih_l[tid] = p.bih[(tid >> 3) * HID + blk * 8 + (tid & 7)];
    bhh_l[tid] = p.bhh[(tid >> 3) * HID + blk * 8 + (tid & 7)];
  }
  if (blk < 200) {
    if (tid < 2) b2_lds[tid] = p.b2[blk * 2 + tid];
    if (tid < 200) {
      int q = tid / 100, i = tid % 100;
      w3t_lds[tid] = p.W3[i * 400 + blk * 2 + q];
    }
  }

  // half-unit GRU weights into registers: 24 float4 = 96 VGPRs
  float4 wih[3][4];   // covers Wih row f4 [half*200, half*200+200)
  float4 whh[3][4];   // covers Whh row f4 [half*250, half*250+250)
  const float4 z4 = make_float4(0.f, 0.f, 0.f, 0.f);
#pragma unroll
  for (int g = 0; g < 3; ++g) {
    const float4* rw = (const float4*)(p.Wih + (size_t)(g * HID + u) * H1) + half * 200;
#pragma unroll
    for (int j = 0; j < 4; ++j) {
      int fi = lane + 64 * j;
      wih[g][j] = (fi < 200) ? rw[fi] : z4;
    }
    const float4* rv = (const float4*)(p.Whh + (size_t)(g * HID + u) * HID) + half * 250;
#pragma unroll
    for (int j = 0; j < 4; ++j) {
      int fi = lane + 64 * j;
      whh[g][j] = (fi < 250) ? rv[fi] : z4;
    }
  }

  // barrier/delta init (ws poisoned 0xAA before every launch)
  if (blk == 0) {
    for (int i = tid; i < 2 * 8 * 160; i += NTHR) p.delta[i] = 0.f;
    __syncthreads();
    if (tid == 0) {
      __hip_atomic_store(p.bar + 0,  0u, __ATOMIC_RELAXED, __HIP_MEMORY_SCOPE_AGENT);
      __hip_atomic_store(p.bar + 32, 0u, __ATOMIC_RELAXED, __HIP_MEMORY_SCOPE_AGENT);
      __threadfence();
      __hip_atomic_store(p.bar + 64, RMAGIC, __ATOMIC_RELAXED, __HIP_MEMORY_SCOPE_AGENT);
    }
  } else {
    if (tid == 0) {
      while (__hip_atomic_load(p.bar + 64, __ATOMIC_RELAXED, __HIP_MEMORY_SCOPE_AGENT) != RMAGIC)
        __builtin_amdgcn_s_sleep(1);
      __threadfence();
    }
  }
  __syncthreads();

  // ---------------- main loop ----------------
  for (int t = 0; t <= T_STEPS; ++t) {
    if (wv == 0) {
      const bool act = lane < 10;
      if (t > 0) {
        float pr_old = act ? prior_lds[lane] : 0.f;
        float dsum = 0.f;
        if (act) {
          const float* dbase = p.delta + ((t - 1) & 1) * 1280 + lane * 16;
#pragma unroll
          for (int c = 0; c < 8; ++c) dsum += dbase[c * 160];
        }
        float b3f = 0.f;
        if (act) {
#pragma unroll
          for (int c = 0; c < 10; ++c) b3f = fmaf(innov_lds[c], b3_lds[lane * 10 + c], b3f);
        }
        float postn = pr_old + dsum + b3f;
        if (act) {
          prpv_lds[lane] = pr_old;
          post_lds[lane] = postn;
          if (blk == 0) p.out[lane * T_STEPS + (t - 1)] = postn;
        }
      }
      if (t < T_STEPS) {
        float pr = 0.f;
        if (act) {
#pragma unroll
          for (int j = 0; j < 10; ++j) pr = fmaf(f_lds[lane * 10 + j], post_lds[j], pr);
          prior_lds[lane] = pr;
        }
        float m1y = 0.f;
#pragma unroll
        for (int j = 0; j < 10; ++j) {
          float prj = __shfl(pr, j, 64);
          if (act) m1y = fmaf(h_lds[lane * 10 + j], prj, m1y);
        }
        float yv  = act ? p.y[lane * T_STEPS + t] : 0.f;
        float inn = act ? (yv - m1y) : 0.f;
        float s1 = inn * inn;
#pragma unroll
        for (int o = 8; o > 0; o >>= 1) s1 += __shfl_xor(s1, o, 16);
        float dm1y = inn / fmaxf(sqrtf(s1), 1e-12f);
        float dx = act ? (post_lds[lane] - prpv_lds[lane]) : 0.f;
        float s2 = dx * dx;
#pragma unroll
        for (int o = 8; o > 0; o >>= 1) s2 += __shfl_xor(s2, o, 16);
        float dm1x = dx / fmaxf(sqrtf(s2), 1e-12f);
        if (act) {
          xin_lds[lane]      = dm1y;
          xin_lds[10 + lane] = dm1x;
          innov_lds[lane]    = inn;
        }
      }
    }
    if (t == T_STEPS) break;
    __syncthreads();

    // a1 = relu(W1 @ x_in + b1); W1 streamed from L2 (read-only resident)
#pragma unroll
    for (int k = 0; k < 2; ++k) {
      int r = tid + NTHR * k;
      if (r < H1) {
        const float4* w1r = (const float4*)(p.W1 + (size_t)r * 20);
        float acc = p.b1[r];
#pragma unroll
        for (int q = 0; q < 5; ++q) {
          float4 w = w1r[q];
          acc = fmaf(w.x, xin_lds[q * 4 + 0], acc);
          acc = fmaf(w.y, xin_lds[q * 4 + 1], acc);
          acc = fmaf(w.z, xin_lds[q * 4 + 2], acc);
          acc = fmaf(w.w, xin_lds[q * 4 + 3], acc);
        }
        a1_lds[r] = fmaxf(acc, 0.f);
      }
    }
    __syncthreads();

    // PhaseA: half-unit gate partials from register weights
    {
      float s_r = 0.f, s_z = 0.f, s_ni = 0.f, s_nh = 0.f;
      const float4* a1v = (const float4*)a1_lds + half * 200;
#pragma unroll
      for (int j = 0; j < 4; ++j) {
        float4 x = a1v[lane + 64 * j];          // pads zeroed, weights zeroed
        s_r  = dot4(wih[0][j], x, s_r);
        s_z  = dot4(wih[1][j], x, s_z);
        s_ni = dot4(wih[2][j], x, s_ni);
      }
      const float4* hnv = (const float4*)hn_lds + half * 250;
#pragma unroll
      for (int j = 0; j < 4; ++j) {
        float4 x = hnv[lane + 64 * j];
        s_r  = dot4(whh[0][j], x, s_r);
        s_z  = dot4(whh[1][j], x, s_z);
        s_nh = dot4(whh[2][j], x, s_nh);
      }
      s_r  = wave_reduce(s_r);
      s_z  = wave_reduce(s_z);
      s_ni = wave_reduce(s_ni);
      s_nh = wave_reduce(s_nh);
      if (lane == 0) {
        gpart_lds[wv][0] = s_r;  gpart_lds[wv][1] = s_z;
        gpart_lds[wv][2] = s_ni; gpart_lds[wv][3] = s_nh;
      }
    }
    __syncthreads();
    if (tid < 8) {   // combine halves, gates, write hn_new[u]
      int q = tid;
      float gr  = gpart_lds[2 * q][0] + gpart_lds[2 * q + 1][0] + bih_l[q]      + bhh_l[q];
      float gz  = gpart_lds[2 * q][1] + gpart_lds[2 * q + 1][1] + bih_l[8 + q]  + bhh_l[8 + q];
      float gni = gpart_lds[2 * q][2] + gpart_lds[2 * q + 1][2] + bih_l[16 + q];
      float gnh = gpart_lds[2 * q][3] + gpart_lds[2 * q + 1][3] + bhh_l[16 + q];
      float rg = sigm(gr);
      float zg = sigm(gz);
      float ng = tanhf(gni + rg * gnh);
      float hold = hn_lds[blk * 8 + q];
      float hnew = (1.f - zg) * ng + zg * hold;
      p.hn_g[(t & 1) * HID + blk * 8 + q] = hnew;
    }
    gbar(p.bar + 0, p.bar + 32);

    // PhaseB: stage hn_new; W2 rows (1 f4/lane); W3-fold -> 8-copy atomics
    {
      const int par = t & 1;
      if (tid < 500)
        ((float4*)hn_lds)[tid] = ((const float4*)(p.hn_g + par * HID))[tid];
      __syncthreads();
      if (blk < 200) {
        const int row = blk * 2 + (wv >> 3);
        const int c   = wv & 7;
        const int fi  = c * 64 + lane;
        float acc = 0.f;
        if (fi < 500) {
          const float4* w2v = (const float4*)(p.W2 + (size_t)row * HID);
          acc = dot4(w2v[fi], ((const float4*)hn_lds)[fi], 0.f);
        }
        acc = wave_reduce(acc);
        if (lane == 0) a2part_lds[wv] = acc;
      }
      __syncthreads();
      if (blk < 200 && tid < 2) {
        float s = b2_lds[tid];
#pragma unroll
        for (int k = 0; k < 8; ++k) s += a2part_lds[tid * 8 + k];
        a2_lds[tid] = fmaxf(s, 0.f);
      }
      __syncthreads();
      if (blk < 200 && wv == 0 && lane < 20) {
        int q = lane / 10, col = lane % 10;
        float mr = 0.f;
#pragma unroll
        for (int c = 0; c < 10; ++c)
          mr = fmaf(innov_lds[c], w3t_lds[q * 100 + col * 10 + c], mr);
        float v = a2_lds[q] * mr;
        float v2 = __shfl(v, lane + 10, 64);
        if (lane < 10)
          atomicAdd(&p.delta[par * 1280 + (blk & 7) * 160 + lane * 16], v + v2);
      }
      if (blk == 0)
        for (int i = tid; i < 1280; i += NTHR) p.delta[(par ^ 1) * 1280 + i] = 0.f;
    }
    gbar(p.bar + 0, p.bar + 32);
  }
}

extern "C" void kernel_launch(void* const* d_in, const int* in_sizes, int n_in,
                              void* d_out, int out_size, void* d_ws, size_t ws_size,
                              hipStream_t stream) {
  Params p;
  p.y    = (const float*)d_in[0];
  p.f    = (const float*)d_in[1];
  p.h    = (const float*)d_in[2];
  p.m1x0 = (const float*)d_in[3];
  p.hn0  = (const float*)d_in[4];
  p.W1   = (const float*)d_in[5];
  p.b1   = (const float*)d_in[6];
  p.Wih  = (const float*)d_in[7];
  p.Whh  = (const float*)d_in[8];
  p.bih  = (const float*)d_in[9];
  p.bhh  = (const float*)d_in[10];
  p.W2   = (const float*)d_in[11];
  p.b2   = (const float*)d_in[12];
  p.W3   = (const float*)d_in[13];
  p.b3   = (const float*)d_in[14];
  p.out  = (float*)d_out;

  float* ws = (float*)d_ws;
  p.hn_g  = ws;                       // 4000 floats
  p.delta = ws + 4000;                // 2560 floats (2 x 8 x 160)
  p.bar   = (unsigned*)(ws + 6592);   // 64B-aligned slots

  void* args[] = { &p };
  hipLaunchCooperativeKernel((const void*)knet_kernel, dim3(NBLK), dim3(NTHR),
                             args, 0, stream);
}